// Round 1
// baseline (430.675 us; speedup 1.0000x reference)
//
#include <hip/hip_runtime.h>
#include <climits>

// ---------------------------------------------------------------------------
// GCN 2-layer + graclus-style pooling, restructured:
//   deg/CSR build (full E)  ->  first-cluster selection (batch only)
//   -> frontier mark (512 sel nodes + in-neighbors, ~8.7k nodes)
//   -> aggregate raw x (128-d) at frontier  -> rowwise GEMM @W1 + b1
//   -> aggregate h1 (64-d) at 512 sel nodes -> rowwise GEMM @W2 + b2
//   -> pairwise max -> out
// Linearity: segment_sum(norm * (x@W)[src]) == segment_sum(norm * x[src]) @ W
// ---------------------------------------------------------------------------

__global__ void k_init(float* deg, int* counts, int* mark, int* first, int* cnt,
                       int n, int nb) {
  int i = blockIdx.x * blockDim.x + threadIdx.x;
  if (i < n) { deg[i] = 1.0f; counts[i] = 0; mark[i] = 0; }
  if (i < nb) first[i] = INT_MAX;
  if (i == 0) *cnt = 0;
}

__global__ void k_count(const int* __restrict__ dst, const float* __restrict__ w,
                        float* deg, int* counts, int e) {
  int i = blockIdx.x * blockDim.x + threadIdx.x;
  if (i >= e) return;
  int d = dst[i];
  atomicAdd(&deg[d], w[i]);
  atomicAdd(&counts[d], 1);
}

__global__ void k_dinv(const float* __restrict__ deg, float* dinv, int n) {
  int i = blockIdx.x * blockDim.x + threadIdx.x;
  if (i < n) { float d = deg[i]; dinv[i] = d > 0.f ? rsqrtf(d) : 0.f; }
}

// --- 3-kernel exclusive scan of counts -> rowptr (+cursor copy) -------------
__global__ __launch_bounds__(1024) void k_scan1(const int* __restrict__ counts,
                                                int* rowptr, int* blocksum, int n) {
  __shared__ int sd[1024];
  int t = threadIdx.x;
  int i = blockIdx.x * 1024 + t;
  int v = (i < n) ? counts[i] : 0;
  sd[t] = v; __syncthreads();
  for (int off = 1; off < 1024; off <<= 1) {
    int a = (t >= off) ? sd[t - off] : 0;
    __syncthreads();
    sd[t] += a;
    __syncthreads();
  }
  if (i < n) rowptr[i] = sd[t] - v;          // block-local exclusive
  if (t == 1023) blocksum[blockIdx.x] = sd[t];
}

__global__ void k_scan2(int* bs, int nb) {   // in-place exclusive scan (chunked)
  __shared__ int sd[128];
  __shared__ int carry;
  int t = threadIdx.x;
  if (t == 0) carry = 0;
  __syncthreads();
  for (int base = 0; base < nb; base += 128) {
    int i = base + t;
    int v = (i < nb) ? bs[i] : 0;
    sd[t] = v; __syncthreads();
    for (int off = 1; off < 128; off <<= 1) {
      int a = (t >= off) ? sd[t - off] : 0;
      __syncthreads();
      sd[t] += a;
      __syncthreads();
    }
    int incl = sd[t];
    int c = carry;
    if (i < nb) bs[i] = c + incl - v;
    __syncthreads();
    if (t == 127) carry = c + incl;
    __syncthreads();
  }
}

__global__ void k_scan3(int* rowptr, int* cursor, const int* __restrict__ blockoff,
                        int n, int e) {
  int i = blockIdx.x * blockDim.x + threadIdx.x;
  if (i < n) {
    int r = rowptr[i] + blockoff[i >> 10];
    rowptr[i] = r;
    cursor[i] = r;
  }
  if (i == n) rowptr[n] = e;
}

__global__ void k_scatter(const int* __restrict__ src, const int* __restrict__ dst,
                          const float* __restrict__ w, const float* __restrict__ dinv,
                          int* cursor, int* cols, float* vals, int e) {
  int i = blockIdx.x * blockDim.x + threadIdx.x;
  if (i >= e) return;
  int s = src[i], d = dst[i];
  int p = atomicAdd(&cursor[d], 1);
  cols[p] = s;
  vals[p] = dinv[s] * w[i] * dinv[d];
}

// --- pooling selection (depends only on batch) ------------------------------
__global__ void k_first(const int* __restrict__ batch, int* first, int nc) {
  int c = blockIdx.x * blockDim.x + threadIdx.x;
  if (c >= nc) return;
  int b0 = batch[2 * c], b1 = batch[2 * c + 1];
  atomicMin(&first[min(b0, b1)], c);
}

__global__ void k_sel(const int* __restrict__ first, int* sel, int nb, int nc) {
  int t = blockIdx.x * blockDim.x + threadIdx.x;
  if (t >= 2 * nb) return;
  int f = first[t >> 1];
  f = min(f, nc - 1);           // JAX gather clamps INT_MAX (empty segment) case
  sel[t] = 2 * f + (t & 1);
}

__global__ void k_mark(const int* __restrict__ sel, const int* __restrict__ rowptr,
                       const int* __restrict__ cols, int* mark, int nsel) {
  int t = blockIdx.x * blockDim.x + threadIdx.x;
  if (t >= nsel) return;
  int i = sel[t];
  mark[i] = 1;
  int beg = rowptr[i], end = rowptr[i + 1];
  for (int p = beg; p < end; ++p) mark[cols[p]] = 1;
}

__global__ void k_compact(const int* __restrict__ mark, int* list, int* cnt, int n) {
  int i = blockIdx.x * blockDim.x + threadIdx.x;
  if (i < n && mark[i]) { int p = atomicAdd(cnt, 1); list[p] = i; }
}

// --- 128-d aggregation of raw x at frontier nodes (wave per node) -----------
__global__ void k_aggx(const float* __restrict__ x, const int* __restrict__ list,
                       const int* __restrict__ cnt, const int* __restrict__ rowptr,
                       const int* __restrict__ cols, const float* __restrict__ vals,
                       const float* __restrict__ dinv, float* __restrict__ aggx) {
  int lane = threadIdx.x & 63;
  int wid = (blockIdx.x * blockDim.x + threadIdx.x) >> 6;
  int nw = (gridDim.x * blockDim.x) >> 6;
  int m = *cnt;
  const float2* x2 = (const float2*)x;   // lane handles dims {2*lane, 2*lane+1}
  float2* a2 = (float2*)aggx;
  for (int li = wid; li < m; li += nw) {
    int i = list[li];
    float dv = dinv[i];
    float2 xi = x2[(size_t)i * 64 + lane];
    float2 acc;
    acc.x = dv * dv * xi.x;
    acc.y = dv * dv * xi.y;
    int beg = rowptr[i], end = rowptr[i + 1];
    for (int p = beg; p < end; ++p) {
      int c = cols[p];
      float v = vals[p];
      float2 xc = x2[(size_t)c * 64 + lane];
      acc.x += v * xc.x;
      acc.y += v * xc.y;
    }
    a2[(size_t)i * 64 + lane] = acc;
  }
}

// --- rowwise GEMM: out[r] = A[r] @ W + bias, rows from list (or identity) ---
template <int K>
__global__ void k_gemm_rows(const float* __restrict__ A, const float* __restrict__ W,
                            const float* __restrict__ bias, const int* __restrict__ list,
                            const int* __restrict__ cntp, int ncap,
                            float* __restrict__ out) {
  __shared__ float Wl[K * 64];
  int t = threadIdx.x;
  for (int p = t; p < K * 16; p += blockDim.x)
    ((float4*)Wl)[p] = ((const float4*)W)[p];
  __syncthreads();
  int lane = t & 63;
  int wid = (blockIdx.x * blockDim.x + t) >> 6;
  int nw = (gridDim.x * blockDim.x) >> 6;
  int m = cntp ? *cntp : ncap;
  for (int li = wid; li < m; li += nw) {
    int r = list ? list[li] : li;
    const float* a = A + (size_t)r * K;
    float acc = bias[lane];
#pragma unroll
    for (int k = 0; k < K; k += 4) {
      float4 av = *(const float4*)(a + k);   // broadcast across lanes
      acc += av.x * Wl[(k + 0) * 64 + lane] + av.y * Wl[(k + 1) * 64 + lane] +
             av.z * Wl[(k + 2) * 64 + lane] + av.w * Wl[(k + 3) * 64 + lane];
    }
    out[(size_t)r * 64 + lane] = acc;
  }
}

// --- 64-d aggregation of h1 at the 512 selected nodes (out by list pos) -----
__global__ void k_aggh(const float* __restrict__ h1, const int* __restrict__ sel,
                       const int* __restrict__ rowptr, const int* __restrict__ cols,
                       const float* __restrict__ vals, const float* __restrict__ dinv,
                       float* __restrict__ aggh, int nsel) {
  int lane = threadIdx.x & 63;
  int wid = (blockIdx.x * blockDim.x + threadIdx.x) >> 6;
  if (wid >= nsel) return;
  int i = sel[wid];
  float dv = dinv[i];
  float acc = dv * dv * h1[(size_t)i * 64 + lane];
  int beg = rowptr[i], end = rowptr[i + 1];
  for (int p = beg; p < end; ++p)
    acc += vals[p] * h1[(size_t)cols[p] * 64 + lane];
  aggh[(size_t)wid * 64 + lane] = acc;
}

__global__ void k_out(const float* __restrict__ h2, float* __restrict__ out, int nb) {
  int j = threadIdx.x;
  int b = blockIdx.x;
  if (b >= nb) return;
  out[(size_t)b * 64 + j] =
      fmaxf(h2[(size_t)(2 * b) * 64 + j], h2[(size_t)(2 * b + 1) * 64 + j]);
}

extern "C" void kernel_launch(void* const* d_in, const int* in_sizes, int n_in,
                              void* d_out, int out_size, void* d_ws, size_t ws_size,
                              hipStream_t stream) {
  const float* x     = (const float*)d_in[0];
  const int*   ei    = (const int*)d_in[1];
  const float* ew    = (const float*)d_in[2];
  const int*   batch = (const int*)d_in[3];
  const float* W1    = (const float*)d_in[4];
  const float* b1    = (const float*)d_in[5];
  const float* W2    = (const float*)d_in[6];
  const float* b2    = (const float*)d_in[7];

  const int E  = in_sizes[2];
  const int N  = in_sizes[3];
  const int B  = out_size / 64;
  const int NC = N / 2;
  const int* srcI = ei;
  const int* dstI = ei + E;

  char* p = (char*)d_ws;
  auto alloc = [&](size_t bytes) -> char* {
    char* r = p;
    p += (bytes + 255) & ~size_t(255);
    return r;
  };
  float* deg      = (float*)alloc((size_t)N * 4);
  float* dinv     = (float*)alloc((size_t)N * 4);
  int*   counts   = (int*)alloc((size_t)N * 4);
  int*   rowptr   = (int*)alloc((size_t)(N + 1) * 4);
  int*   cursor   = (int*)alloc((size_t)N * 4);
  int*   blocksum = (int*)alloc(1024 * 4);
  int*   cols     = (int*)alloc((size_t)E * 4);
  float* vals     = (float*)alloc((size_t)E * 4);
  int*   mark     = (int*)alloc((size_t)N * 4);
  int*   list     = (int*)alloc((size_t)N * 4);
  int*   first    = (int*)alloc((size_t)B * 4);
  int*   sel      = (int*)alloc((size_t)2 * B * 4);
  int*   cnt      = (int*)alloc(256);
  float* aggx     = (float*)alloc((size_t)N * 128 * 4);
  float* h1       = (float*)alloc((size_t)N * 64 * 4);
  float* aggh     = (float*)alloc((size_t)2 * B * 64 * 4);
  float* h2       = (float*)alloc((size_t)2 * B * 64 * 4);

  int gN  = (N + 255) / 256;
  int gE  = (E + 255) / 256;
  int nb1 = (N + 1023) / 1024;

  k_init<<<gN, 256, 0, stream>>>(deg, counts, mark, first, cnt, N, B);
  k_count<<<gE, 256, 0, stream>>>(dstI, ew, deg, counts, E);
  k_dinv<<<gN, 256, 0, stream>>>(deg, dinv, N);
  k_scan1<<<nb1, 1024, 0, stream>>>(counts, rowptr, blocksum, N);
  k_scan2<<<1, 128, 0, stream>>>(blocksum, nb1);
  k_scan3<<<(N + 256) / 256, 256, 0, stream>>>(rowptr, cursor, blocksum, N, E);
  k_scatter<<<gE, 256, 0, stream>>>(srcI, dstI, ew, dinv, cursor, cols, vals, E);
  k_first<<<(NC + 255) / 256, 256, 0, stream>>>(batch, first, NC);
  k_sel<<<(2 * B + 255) / 256, 256, 0, stream>>>(first, sel, B, NC);
  k_mark<<<(2 * B + 255) / 256, 256, 0, stream>>>(sel, rowptr, cols, mark, 2 * B);
  k_compact<<<gN, 256, 0, stream>>>(mark, list, cnt, N);
  k_aggx<<<2048, 256, 0, stream>>>(x, list, cnt, rowptr, cols, vals, dinv, aggx);
  k_gemm_rows<128><<<512, 256, 0, stream>>>(aggx, W1, b1, list, cnt, 0, h1);
  k_aggh<<<(2 * B + 3) / 4, 256, 0, stream>>>(h1, sel, rowptr, cols, vals, dinv, aggh, 2 * B);
  k_gemm_rows<64><<<(2 * B + 3) / 4, 256, 0, stream>>>(aggh, W2, b2, nullptr, nullptr, 2 * B, h2);
  k_out<<<B, 64, 0, stream>>>(h2, (float*)d_out, B);
}